// Round 4
// baseline (43.912 us; speedup 1.0000x reference)
//
#include <hip/hip_runtime.h>
#include <math.h>

#define LMAX   6
#define NRAD   20
#define NELEM  4
#define NBATCH 2000
#define NPTS   100000
#define NLMTOT 49            // (LMAX+1)^2
#define OUTROW 3920          // NELEM * 980
#define PROW   84            // words per P row: [0:49 Y][49:52 pad][52+8g+j : rad n=5g+j, j<5]
#define PROW4  21            // float4 per row
#define APTS   64            // points per feat block (1 wave)
#define GPTS   16            // points staged per accum group
#define PI_F   3.14159265358979323846f
#define RADK   0.44721359549995793f   // sqrt(2/RC), RC=10
#define INV_RC 0.1f
#define P_OFF  16384         // byte offset of P inside d_ws

// --- seg[b] = lower_bound(batch_ids, b), b in [0, NBATCH] ---
__global__ __launch_bounds__(256) void seg_kernel(
    const int* __restrict__ batch_ids, int* __restrict__ seg)
{
  int b = blockIdx.x * blockDim.x + threadIdx.x;
  if (b > NBATCH) return;
  int lo = 0, hi = NPTS;
  while (lo < hi) { int mid = (lo + hi) >> 1; if (batch_ids[mid] < b) lo = mid + 1; else hi = mid; }
  seg[b] = lo;
}

// --- dense pointwise features, 1 wave per block ---
__global__ __launch_bounds__(64) void feat_kernel(
    const float* __restrict__ coords, float* __restrict__ Pg)
{
  const int t = threadIdx.x;
  const int base_pt = blockIdx.x * APTS;
  const int valid = min(APTS, NPTS - base_pt);

  __shared__ float sL[PROW][APTS + 1];   // feature-major, odd stride
  __shared__ float sC[NLMTOT];

  if (t < NLMTOT) {
    int lm = t, l = 0;
    #pragma unroll
    for (int ll = 1; ll <= LMAX; ++ll) if (lm >= ll * ll) l = ll;
    int m  = lm - l * l - l;
    int am = m < 0 ? -m : m;
    float denom = 1.f;
    for (int k = l - am + 1; k <= l + am; ++k) denom *= (float)k;
    float nlm = sqrtf((float)(2 * l + 1) / denom);
    sC[lm] = (m == 0) ? nlm : 1.4142135623730951f * nlm;
  }
  __syncthreads();

  if (t < valid) {
    int p = base_pt + t;
    float x = coords[3 * p + 0], y = coords[3 * p + 1], z = coords[3 * p + 2];
    float r    = sqrtf(x * x + y * y + z * z);
    float invr = 1.f / r;
    x *= invr; y *= invr; z *= invr;

    float cs[LMAX + 1], sn[LMAX + 1];
    cs[0] = 1.f; sn[0] = 0.f;
    #pragma unroll
    for (int m = 1; m <= LMAX; ++m) {
      cs[m] = cs[m - 1] * x - sn[m - 1] * y;
      sn[m] = sn[m - 1] * x + cs[m - 1] * y;
    }
    float Q[LMAX + 1][LMAX + 1];
    Q[0][0] = 1.f;
    #pragma unroll
    for (int m = 1; m <= LMAX; ++m) Q[m][m] = -(float)(2 * m - 1) * Q[m - 1][m - 1];
    #pragma unroll
    for (int m = 0; m < LMAX; ++m) Q[m + 1][m] = (float)(2 * m + 1) * z * Q[m][m];
    #pragma unroll
    for (int m = 0; m <= LMAX; ++m) {
      #pragma unroll
      for (int ll = m + 2; ll <= LMAX; ++ll) {
        Q[ll][m] = ((float)(2 * ll - 1) * z * Q[ll - 1][m]
                  - (float)(ll + m - 1) * Q[ll - 2][m]) / (float)(ll - m);
      }
    }
    #pragma unroll
    for (int ll = 0; ll <= LMAX; ++ll) {
      #pragma unroll
      for (int m = -ll; m <= ll; ++m) {
        int am = m < 0 ? -m : m;
        float v = Q[ll][am] * sC[ll * ll + ll + m];
        if (m < 0)      v *= sn[am];
        else if (m > 0) v *= cs[am];
        sL[ll * ll + ll + m][t] = v;
      }
    }
    // radial: sin(n*a) via Chebyshev recurrence; store tiled: word 52+8g+j = n=5g+j
    float a = PI_F * r * INV_RC;
    float s1, c1;
    __sincosf(a, &s1, &c1);
    float twoc = 2.f * c1;
    float sprev = 0.f, scur = s1;
    float scale = RADK * invr;
    #pragma unroll
    for (int n = 0; n < NRAD; ++n) {
      sL[52 + 8 * (n / 5) + (n % 5)][t] = scale * scur;
      float snext = twoc * scur - sprev;
      sprev = scur; scur = snext;
    }
  }
  __syncthreads();

  // coalesced float4 store (pad lanes carry garbage; never consumed)
  float4* out4 = (float4*)(Pg + (size_t)base_pt * PROW);
  for (int w = t; w < valid * PROW4; w += APTS) {
    int pi = w / PROW4;
    int fj = (w - pi * PROW4) * 4;
    float4 v;
    v.x = sL[fj + 0][pi];
    v.y = sL[fj + 1][pi];
    v.z = sL[fj + 2][pi];
    v.w = sL[fj + 3][pi];
    out4[w] = v;
  }
}

// --- gather + segment-accumulate: 1 wave per (batch, elem) ---
__global__ __launch_bounds__(64) void accum_kernel(
    const int*    __restrict__ elem_ids,
    const int*    __restrict__ seg,
    const float4* __restrict__ P4,
    float*        __restrict__ out)
{
  const int b = blockIdx.x >> 2;
  const int e = blockIdx.x & 3;
  const int t = threadIdx.x;

  __shared__ __align__(16) float sP[GPTS * PROW];   // 5.4 KB
  __shared__ __align__(16) float sOut[980];
  __shared__ int sIdxW[64];

  const int start = seg[b], end = seg[b + 1];

  const int tl = t & 15;    // lm tile: lm in {4tl..4tl+3}
  const int tn = t >> 4;    // n  tile: n  in {5tn..5tn+4}

  float acc[4][5];
  #pragma unroll
  for (int i = 0; i < 4; ++i)
    #pragma unroll
    for (int j = 0; j < 5; ++j) acc[i][j] = 0.f;

  for (int c = start; c < end; c += 64) {
    int wcnt = end - c; if (wcnt > 64) wcnt = 64;
    bool match = (t < wcnt) && (elem_ids[c + t] == e);
    unsigned long long mask = __ballot(match);
    int mcnt = __popcll(mask);
    int slot = __popcll(mask & ((1ULL << t) - 1ULL));
    if (match) sIdxW[slot] = c + t;
    __syncthreads();

    for (int g0 = 0; g0 < mcnt; g0 += GPTS) {
      int gcnt = mcnt - g0; if (gcnt > GPTS) gcnt = GPTS;
      int nf4 = gcnt * PROW4;
      for (int w = t; w < nf4; w += 64) {
        int pi = w / PROW4, fi = w - pi * PROW4;
        ((float4*)sP)[pi * PROW4 + fi] = P4[(size_t)sIdxW[g0 + pi] * PROW4 + fi];
      }
      __syncthreads();

      for (int p = 0; p < gcnt; ++p) {
        const float* row = sP + p * PROW;
        float4 yv = *(const float4*)(row + 4 * tl);
        float4 ra = *(const float4*)(row + 52 + 8 * tn);
        float  r5 = row[52 + 8 * tn + 4];
        float yy[4] = {yv.x, yv.y, yv.z, yv.w};
        float rr[5] = {ra.x, ra.y, ra.z, ra.w, r5};
        #pragma unroll
        for (int i = 0; i < 4; ++i)
          #pragma unroll
          for (int j = 0; j < 5; ++j)
            acc[i][j] += yy[i] * rr[j];
      }
      __syncthreads();
    }
  }

  // --- epilogue: acc -> sOut (feature-ordered), then coalesced float4 runs ---
  #pragma unroll
  for (int i = 0; i < 4; ++i) {
    int lm = 4 * tl + i;
    if (lm < NLMTOT) {
      int l = 0;
      #pragma unroll
      for (int ll = 1; ll <= LMAX; ++ll) if (lm >= ll * ll) l = ll;
      int fb = 20 * l * l;
      int mi = lm - l * l;
      int nm = 2 * l + 1;
      #pragma unroll
      for (int j = 0; j < 5; ++j) {
        int n = 5 * tn + j;
        sOut[fb + n * nm + mi] = acc[i][j];
      }
    }
  }
  __syncthreads();

  for (int w = t; w < 245; w += 64) {
    int f0 = 4 * w;
    int lw = 0;
    #pragma unroll
    for (int ll = 1; ll <= LMAX; ++ll) if (f0 >= 20 * ll * ll) lw = ll;
    long long g = (long long)b * OUTROW + 80 * lw * lw
                + (long long)e * 20 * (2 * lw + 1) + (f0 - 20 * lw * lw);
    *(float4*)(out + g) = *(const float4*)(sOut + f0);
  }
}

extern "C" void kernel_launch(void* const* d_in, const int* in_sizes, int n_in,
                              void* d_out, int out_size, void* d_ws, size_t ws_size,
                              hipStream_t stream) {
  const float* coords    = (const float*)d_in[0];
  const int*   elem_ids  = (const int*)d_in[1];
  const int*   batch_ids = (const int*)d_in[2];
  float*       out       = (float*)d_out;
  int*         seg       = (int*)d_ws;                       // NBATCH+1 ints
  float*       Pg        = (float*)((char*)d_ws + P_OFF);    // [NPTS][84]

  seg_kernel<<<(NBATCH + 1 + 255) / 256, 256, 0, stream>>>(batch_ids, seg);
  feat_kernel<<<(NPTS + APTS - 1) / APTS, APTS, 0, stream>>>(coords, Pg);
  accum_kernel<<<NBATCH * NELEM, 64, 0, stream>>>(elem_ids, seg, (const float4*)Pg, out);
}